// Round 5
// baseline (350.262 us; speedup 1.0000x reference)
//
#include <hip/hip_runtime.h>
#include <math.h>

#define B_ 2
#define H_ 16
#define S_ 2048
#define CTX_ 1024
#define VD_ 288
#define VD2_ 576
#define FFN_ 512
#define FFNH_ 256
#define NH1_ 17
#define EPSILON_ 0.066f
#define LN_EPS_ 1e-5f
#define TPB_ 8                    // tokens per block for all MLP kernels
#define NBLK_ (B_ * S_ / TPB_)    // 512 blocks

typedef float vfloat4 __attribute__((ext_vector_type(4)));

__device__ __forceinline__ float gelu_exact(float x) {
    return 0.5f * x * (1.0f + erff(x * 0.70710678118654752440f));
}
__device__ __forceinline__ vfloat4 gelu4(vfloat4 v) {
    vfloat4 o;
    o.x = gelu_exact(v.x); o.y = gelu_exact(v.y);
    o.z = gelu_exact(v.z); o.w = gelu_exact(v.w);
    return o;
}

// ---------------- K0: fused histogram (proven round 4) ----------------
__global__ __launch_bounds__(1024) void count_kernel(
    const int* __restrict__ ids, int* __restrict__ counts)
{
    __shared__ int hist[CTX_];
    const int t = threadIdx.x;          // 1024 threads == CTX_
    hist[t] = 0;
    __syncthreads();
    #pragma unroll
    for (int r = 0; r < (B_ * S_) / 1024; ++r)
        atomicAdd(&hist[ids[t + 1024 * r]], 1);
    __syncthreads();
    counts[t] = hist[t];
}

// ---------------- K1: embedding gather + LayerNorm(288) ----------------
// round-0 phase 0 verbatim; result staged in LDS then written as a
// contiguous [blk][288][8] tile (coalesced).
__global__ __launch_bounds__(256) void emb_ln_kernel(
    const int* __restrict__ ids, const float* __restrict__ embW,
    const float* __restrict__ lnvw, const float* __restrict__ lnvb,
    float* __restrict__ va_g)
{
    __shared__ __align__(16) float vaL[VD_ * TPB_];   // [dim][token], 9.2 KB
    const int tid  = threadIdx.x;
    const int blk  = blockIdx.x;
    const int tok0 = blk * TPB_;
    {
        const int tt = tid >> 5;      // 0..7
        const int l  = tid & 31;
        const int id = ids[tok0 + tt];
        float x[9];
        float s = 0.f, sq = 0.f;
        #pragma unroll
        for (int r = 0; r < 9; ++r) {
            float xv = embW[id * VD_ + l + 32 * r];
            x[r] = xv; s += xv; sq += xv * xv;
        }
        #pragma unroll
        for (int m = 16; m >= 1; m >>= 1) {
            s  += __shfl_xor(s,  m, 64);
            sq += __shfl_xor(sq, m, 64);
        }
        float mu   = s * (1.f / VD_);
        float var  = sq * (1.f / VD_) - mu * mu;
        float rstd = rsqrtf(var + LN_EPS_);
        #pragma unroll
        for (int r = 0; r < 9; ++r) {
            int i = l + 32 * r;
            vaL[i * TPB_ + tt] = (x[r] - mu) * rstd * lnvw[i] + lnvb[i];
        }
    }
    __syncthreads();
    #pragma unroll
    for (int j = 0; j < 9; ++j)       // 2304 floats, coalesced
        va_g[blk * (VD_ * TPB_) + tid + 256 * j] = vaL[tid + 256 * j];
}

// ---------------- K2: P1  ha = gelu(va @ pW1 + pb1)  [288 -> 576] ----------------
// 4 waves: (tg = token quad 0/1) x (ch = col half 0/1). Each wave: 4 tokens,
// 288 cols -> per k: 1 broadcast b128 + 4(+1 predicated) weight loads + 18 FMA.
// Per-token weight traffic HALVED vs monolithic (wave serves 4 tokens).
__global__ __launch_bounds__(256) void p1_kernel(
    const float* __restrict__ va_g, const float* __restrict__ pW1,
    const float* __restrict__ pb1, float* __restrict__ ha_g)
{
    __shared__ __align__(16) float vat[VD_ * TPB_];   //  9.2 KB
    __shared__ __align__(16) float haL[VD2_ * TPB_];  // 18.4 KB
    const int tid = threadIdx.x;
    const int blk = blockIdx.x;
    #pragma unroll
    for (int j = 0; j < 9; ++j)       // coalesced load, conflict-free ds_write
        vat[tid + 256 * j] = va_g[blk * (VD_ * TPB_) + tid + 256 * j];
    __syncthreads();

    const int wid  = tid >> 6;
    const int cthr = tid & 63;
    const int tg   = wid & 1;         // token quad
    const int ch   = wid >> 1;        // column half
    const int t0   = 4 * tg;
    const int cb   = VD2_ / 2 * ch;   // 0 or 288

    vfloat4 acc0 = 0, acc1 = 0, acc2 = 0, acc3 = 0, acc4 = 0;
    const bool extra = (cthr < 32);   // cols cb+256 .. cb+287
    for (int k = 0; k < VD_; ++k) {
        vfloat4 v = *(const vfloat4*)&vat[k * TPB_ + t0];   // wave-broadcast
        const float* wrow = &pW1[k * VD2_ + cb + cthr];
        float w0 = wrow[0], w1 = wrow[64], w2 = wrow[128], w3 = wrow[192];
        acc0 += w0 * v; acc1 += w1 * v; acc2 += w2 * v; acc3 += w3 * v;
        if (extra) {
            float w4 = pW1[k * VD2_ + cb + 256 + cthr];
            acc4 += w4 * v;
        }
    }
    {
        int col = cb + cthr;
        *(vfloat4*)&haL[(col      ) * TPB_ + t0] = gelu4(acc0 + pb1[col]);
        *(vfloat4*)&haL[(col +  64) * TPB_ + t0] = gelu4(acc1 + pb1[col + 64]);
        *(vfloat4*)&haL[(col + 128) * TPB_ + t0] = gelu4(acc2 + pb1[col + 128]);
        *(vfloat4*)&haL[(col + 192) * TPB_ + t0] = gelu4(acc3 + pb1[col + 192]);
        if (extra)
            *(vfloat4*)&haL[(col + 256) * TPB_ + t0] = gelu4(acc4 + pb1[col + 256]);
    }
    __syncthreads();
    #pragma unroll
    for (int j = 0; j < 18; ++j)      // 4608 floats, coalesced
        ha_g[blk * (VD2_ * TPB_) + tid + 256 * j] = haL[tid + 256 * j];
}

// ---------------- K3: P2 + occ + LayerNorm(17) + P4 ----------------
// round-0 phases 2..4 with ha read from the global tile and h2 written
// through LDS as a contiguous tile.
__global__ __launch_bounds__(256) void p24_kernel(
    const int* __restrict__ ids, const int* __restrict__ counts,
    const float* __restrict__ ha_g,
    const float* __restrict__ pW2, const float* __restrict__ pb2,
    const float* __restrict__ lncw, const float* __restrict__ lncb,
    const float* __restrict__ fW1, const float* __restrict__ fb1,
    float* __restrict__ h2_g)
{
    __shared__ __align__(16) float comb17[NH1_][TPB_];
    __shared__ __align__(16) float h2L[FFN_ * TPB_];   // 16.4 KB
    const int tid  = threadIdx.x;
    const int blk  = blockIdx.x;
    const int tok0 = blk * TPB_;
    const int wid  = tid >> 6;
    const int cthr = tid & 63;
    const int t0   = wid * 2;
    const float* haT = ha_g + blk * (VD2_ * TPB_);

    // ---- P2: valence = tanh(ha @ pW2 + pb2) + occ ----
    {
        const int col = cthr & 15;
        const int ks  = cthr >> 4;      // 4-way K split (144 each)
        float2 acc = make_float2(0.f, 0.f);
        for (int k = ks * 144; k < ks * 144 + 144; ++k) {
            float2 v = *(const float2*)&haT[k * TPB_ + t0];   // 16-lane broadcast
            float w = pW2[k * H_ + col];
            acc.x += w * v.x; acc.y += w * v.y;
        }
        acc.x += __shfl_xor(acc.x, 16, 64); acc.y += __shfl_xor(acc.y, 16, 64);
        acc.x += __shfl_xor(acc.x, 32, 64); acc.y += __shfl_xor(acc.y, 32, 64);
        if (cthr < 16) {
            float b = pb2[col];
            float2 o = make_float2(tanhf(acc.x + b), tanhf(acc.y + b));
            *(float2*)&comb17[1 + col][t0] = o;
        }
        if (cthr == 16) {
            #pragma unroll
            for (int j = 0; j < 2; ++j) {
                int t = t0 + j;
                int id = ids[tok0 + t];
                float c = (float)counts[id];
                if (c < 1.f) c = 1.f;
                comb17[0][t] = log1pf(c);
            }
        }
    }
    __syncthreads();

    // ---- LayerNorm(17), one thread per token ----
    if (tid < TPB_) {
        float vals[NH1_];
        float s = 0.f;
        #pragma unroll
        for (int i = 0; i < NH1_; ++i) { vals[i] = comb17[i][tid]; s += vals[i]; }
        float mu = s / NH1_;
        float vq = 0.f;
        #pragma unroll
        for (int i = 0; i < NH1_; ++i) { float d = vals[i] - mu; vq += d * d; }
        float r = rsqrtf(vq / NH1_ + LN_EPS_);
        #pragma unroll
        for (int i = 0; i < NH1_; ++i)
            comb17[i][tid] = (vals[i] - mu) * r * lncw[i] + lncb[i];
    }
    __syncthreads();

    // ---- P4: h2 = gelu(comb @ fW1 + fb1) [17 -> 512], round-0 loop ----
    {
        float2 acc[8];
        #pragma unroll
        for (int c = 0; c < 8; ++c) acc[c] = make_float2(0.f, 0.f);
        #pragma unroll
        for (int k = 0; k < NH1_; ++k) {
            float2 v = *(const float2*)&comb17[k][t0];
            const float* wrow = &fW1[k * FFN_ + cthr];
            #pragma unroll
            for (int c = 0; c < 8; ++c) {
                float w = wrow[64 * c];
                acc[c].x += w * v.x; acc[c].y += w * v.y;
            }
        }
        #pragma unroll
        for (int c = 0; c < 8; ++c) {
            int col = cthr + 64 * c;
            float b = fb1[col];
            float2 o = make_float2(gelu_exact(acc[c].x + b), gelu_exact(acc[c].y + b));
            *(float2*)&h2L[col * TPB_ + t0] = o;
        }
    }
    __syncthreads();
    #pragma unroll
    for (int j = 0; j < 16; ++j)      // 4096 floats, coalesced
        h2_g[blk * (FFN_ * TPB_) + tid + 256 * j] = h2L[tid + 256 * j];
}

// ---------------- K4: P5 + P6 + fused scale ----------------
// round-0 phases 5..6, then the block streams its own 8 tokens' 128 rows
// (scores scaling) with wout still in LDS. No global wout, one less launch,
// and the scale starts as soon as each block's tokens are done.
__global__ __launch_bounds__(256) void p56_scale_kernel(
    const float* __restrict__ h2_g,
    const float* __restrict__ fW2, const float* __restrict__ fb2,
    const float* __restrict__ fW3, const float* __restrict__ fb3,
    const vfloat4* __restrict__ scores, vfloat4* __restrict__ out)
{
    __shared__ __align__(16) float h2t[FFN_ * TPB_];   // 16.4 KB
    __shared__ __align__(16) float h3t[FFNH_ * TPB_];  //  8.2 KB
    __shared__ float wl[TPB_];
    const int tid  = threadIdx.x;
    const int blk  = blockIdx.x;
    const int wid  = tid >> 6;
    const int cthr = tid & 63;
    const int t0   = wid * 2;

    #pragma unroll
    for (int j = 0; j < 16; ++j)      // coalesced, conflict-free
        h2t[tid + 256 * j] = h2_g[blk * (FFN_ * TPB_) + tid + 256 * j];
    __syncthreads();

    // ---- P5: h3 = gelu(h2 @ fW2 + fb2) [512 -> 256], round-0 loop ----
    {
        float2 acc[4];
        #pragma unroll
        for (int c = 0; c < 4; ++c) acc[c] = make_float2(0.f, 0.f);
        for (int k = 0; k < FFN_; ++k) {
            float2 v = *(const float2*)&h2t[k * TPB_ + t0];
            const float* wrow = &fW2[k * FFNH_ + cthr];
            #pragma unroll
            for (int c = 0; c < 4; ++c) {
                float w = wrow[64 * c];
                acc[c].x += w * v.x; acc[c].y += w * v.y;
            }
        }
        #pragma unroll
        for (int c = 0; c < 4; ++c) {
            int col = cthr + 64 * c;
            float b = fb2[col];
            float2 o = make_float2(gelu_exact(acc[c].x + b), gelu_exact(acc[c].y + b));
            *(float2*)&h3t[col * TPB_ + t0] = o;
        }
    }
    __syncthreads();

    // ---- P6: mod = tanh(h3 . fW3 + fb3); 32 threads/token ----
    {
        const int tt = tid >> 5;
        const int l  = tid & 31;
        float acc = 0.f;
        #pragma unroll
        for (int r = 0; r < FFNH_ / 32; ++r) {
            int k = l + 32 * r;
            acc += h3t[k * TPB_ + tt] * fW3[k];
        }
        #pragma unroll
        for (int m = 16; m >= 1; m >>= 1) acc += __shfl_xor(acc, m, 64);
        if (l == 0) {
            float mod = tanhf(acc + fb3[0]);
            wl[tt] = 1.0f + EPSILON_ * mod;
        }
    }
    __syncthreads();

    // ---- fused scale: this block's 8 tokens -> 8*16 rows * 2048 floats ----
    // out[b,h,s,:] = scores[b,h,s,:] * wl[token]; 65536 float4s per block.
    const int g0 = blk * TPB_;
    #pragma unroll 4
    for (int m = tid; m < TPB_ * H_ * (S_ / 4); m += 256) {
        int rr  = m >> 9;             // local row 0..127 (512 float4 per row)
        int off = m & 511;
        int j   = rr & 7;             // token within block
        int h   = rr >> 3;            // head
        int g   = g0 + j;
        long row = (long)(g >> 11) * (H_ * S_) + h * S_ + (g & (S_ - 1));
        long idx = row * (S_ / 4) + off;
        vfloat4 x = __builtin_nontemporal_load(&scores[idx]);
        x *= wl[j];
        __builtin_nontemporal_store(x, &out[idx]);
    }
}

extern "C" void kernel_launch(void* const* d_in, const int* in_sizes, int n_in,
                              void* d_out, int out_size, void* d_ws, size_t ws_size,
                              hipStream_t stream) {
    const float* scores = (const float*)d_in[0];
    const int*   ids    = (const int*)  d_in[1];
    const float* embW   = (const float*)d_in[2];
    const float* lnvw   = (const float*)d_in[3];
    const float* lnvb   = (const float*)d_in[4];
    const float* pW1    = (const float*)d_in[5];
    const float* pb1    = (const float*)d_in[6];
    const float* pW2    = (const float*)d_in[7];
    const float* pb2    = (const float*)d_in[8];
    const float* lncw   = (const float*)d_in[9];
    const float* lncb   = (const float*)d_in[10];
    const float* fW1    = (const float*)d_in[11];
    const float* fb1    = (const float*)d_in[12];
    const float* fW2    = (const float*)d_in[13];
    const float* fb2    = (const float*)d_in[14];
    const float* fW3    = (const float*)d_in[15];
    const float* fb3    = (const float*)d_in[16];

    // workspace layout (~22.6 MB): counts | va | ha | h2
    char* ws = (char*)d_ws;
    int*   counts = (int*)ws;                               //   4 KB
    float* va_g   = (float*)(ws + 8192);                    // 4.72 MB
    float* ha_g   = (float*)(ws + 8192 + 4718592);          // 9.44 MB
    float* h2_g   = (float*)(ws + 8192 + 4718592 + 9437184);// 8.39 MB

    count_kernel<<<1, 1024, 0, stream>>>(ids, counts);
    emb_ln_kernel<<<NBLK_, 256, 0, stream>>>(ids, embW, lnvw, lnvb, va_g);
    p1_kernel<<<NBLK_, 256, 0, stream>>>(va_g, pW1, pb1, ha_g);
    p24_kernel<<<NBLK_, 256, 0, stream>>>(ids, counts, ha_g, pW2, pb2,
                                          lncw, lncb, fW1, fb1, h2_g);
    p56_scale_kernel<<<NBLK_, 256, 0, stream>>>(h2_g, fW2, fb2, fW3, fb3,
                                                (const vfloat4*)scores,
                                                (vfloat4*)d_out);
}

// Round 6
// 316.535 us; speedup vs baseline: 1.1066x; 1.1066x over previous
//
#include <hip/hip_runtime.h>
#include <math.h>

#define B_ 2
#define H_ 16
#define S_ 2048
#define CTX_ 1024
#define VD_ 288
#define VD2_ 576
#define FFN_ 512
#define FFNH_ 256
#define NH1_ 17
#define EPSILON_ 0.066f
#define LN_EPS_ 1e-5f
#define TPB_ 16                   // tokens per block
#define NBLK_ (B_ * S_ / TPB_)    // 256 blocks

typedef float vfloat4 __attribute__((ext_vector_type(4)));

__device__ __forceinline__ float gelu_exact(float x) {
    return 0.5f * x * (1.0f + erff(x * 0.70710678118654752440f));
}
__device__ __forceinline__ vfloat4 gelu4(vfloat4 v) {
    vfloat4 o;
    o.x = gelu_exact(v.x); o.y = gelu_exact(v.y);
    o.z = gelu_exact(v.z); o.w = gelu_exact(v.w);
    return o;
}

// one-block fused histogram (proven round 4)
__global__ __launch_bounds__(1024) void count_kernel(
    const int* __restrict__ ids, int* __restrict__ counts)
{
    __shared__ int hist[CTX_];
    const int t = threadIdx.x;          // 1024 threads == CTX_
    hist[t] = 0;
    __syncthreads();
    #pragma unroll
    for (int r = 0; r < (B_ * S_) / 1024; ++r)
        atomicAdd(&hist[ids[t + 1024 * r]], 1);
    __syncthreads();
    counts[t] = hist[t];
}

// Round-4 monolithic kernel (512 thr, TPB=16, proven 311.7) with phases
// 1/4/5 re-tiled: 8 waves = 4 token-quads x 2 column-halves. Each wave
// serves 4 tokens and HALF the columns -> per-wave weight bytes halved
// (P1 648->331 KB, P4 34->17, P5 512->256), FMA count identical, load fan
// kept >= 2 (4.5 for P1). One vfloat4 LDS broadcast per k, unchanged.
__global__ __launch_bounds__(512) void token_mlp_kernel(
    const int* __restrict__ ids, const int* __restrict__ counts,
    const float* __restrict__ embW,
    const float* __restrict__ lnvw, const float* __restrict__ lnvb,
    const float* __restrict__ pW1, const float* __restrict__ pb1,
    const float* __restrict__ pW2, const float* __restrict__ pb2,
    const float* __restrict__ lncw, const float* __restrict__ lncb,
    const float* __restrict__ fW1, const float* __restrict__ fb1,
    const float* __restrict__ fW2, const float* __restrict__ fb2,
    const float* __restrict__ fW3, const float* __restrict__ fb3,
    float* __restrict__ wout)
{
    // activations transposed: [dim][token]; row = 64 B (16-aligned at quad)
    __shared__ __align__(16) float va[VD_][TPB_];      // 18.4 KB
    __shared__ __align__(16) float ha[VD2_][TPB_];     // 36.9 KB
    __shared__ __align__(16) float comb17[NH1_][TPB_]; //  1.1 KB
    __shared__ __align__(16) float h2a[FFN_][TPB_];    // 32.8 KB
    __shared__ __align__(16) float h3a[FFNH_][TPB_];   // 16.4 KB
    // total 105.6 KB -> 1 block/CU, 8 waves = 2 waves/SIMD

    const int tid  = threadIdx.x;
    const int tok0 = blockIdx.x * TPB_;
    const int wid  = tid >> 6;     // wave 0..7
    const int cthr = tid & 63;
    const int t0   = (wid & 3) * 2 + (wid >> 2) * 8; // pair id for phase 2 (any 1:1 map ok)
    const int quad = wid & 3;      // token quad for tiled phases
    const int ch   = wid >> 2;     // column half
    const int tq   = quad * 4;

    // ---- phase 0: embedding gather + LayerNorm(288); 32 threads/token ----
    {
        const int tt = tid >> 5;      // 0..15
        const int l  = tid & 31;
        const int id = ids[tok0 + tt];
        float x[9];
        float s = 0.f, sq = 0.f;
        #pragma unroll
        for (int r = 0; r < 9; ++r) {
            float xv = embW[id * VD_ + l + 32 * r];
            x[r] = xv; s += xv; sq += xv * xv;
        }
        #pragma unroll
        for (int m = 16; m >= 1; m >>= 1) {
            s  += __shfl_xor(s,  m, 64);
            sq += __shfl_xor(sq, m, 64);
        }
        float mu   = s * (1.f / VD_);
        float var  = sq * (1.f / VD_) - mu * mu;
        float rstd = rsqrtf(var + LN_EPS_);
        #pragma unroll
        for (int r = 0; r < 9; ++r) {
            int i = l + 32 * r;
            va[i][tt] = (x[r] - mu) * rstd * lnvw[i] + lnvb[i];
        }
    }
    __syncthreads();

    // ---- phase 1: ha = gelu(va @ pW1 + pb1)  [288 -> 576] ----
    // wave = 4 tokens x 288 cols; per k: 1 vfloat4 broadcast + 4(+1) loads + 18 FMA
    {
        vfloat4 a0 = 0, a1 = 0, a2 = 0, a3 = 0, a4 = 0;
        const int cb = (VD2_ / 2) * ch;        // 0 or 288
        const bool extra = (cthr < 32);        // cols cb+256..cb+287
        for (int k = 0; k < VD_; ++k) {
            vfloat4 v = *(const vfloat4*)&va[k][tq];
            const float* wrow = &pW1[k * VD2_ + cb + cthr];
            float w0 = wrow[0], w1 = wrow[64], w2 = wrow[128], w3 = wrow[192];
            a0 += w0 * v; a1 += w1 * v; a2 += w2 * v; a3 += w3 * v;
            if (extra) a4 += wrow[256] * v;
        }
        int col = cb + cthr;
        *(vfloat4*)&ha[col      ][tq] = gelu4(a0 + pb1[col]);
        *(vfloat4*)&ha[col +  64][tq] = gelu4(a1 + pb1[col + 64]);
        *(vfloat4*)&ha[col + 128][tq] = gelu4(a2 + pb1[col + 128]);
        *(vfloat4*)&ha[col + 192][tq] = gelu4(a3 + pb1[col + 192]);
        if (extra)
            *(vfloat4*)&ha[col + 256][tq] = gelu4(a4 + pb1[col + 256]);
    }
    __syncthreads();

    // ---- phase 2: valence = tanh(ha @ pW2 + pb2) [576 -> 16] + occ ----
    // unchanged round-4 loop; wave owns token pair t0 (t0 covers 0..15 once)
    {
        const int col = cthr & 15;
        const int ks  = cthr >> 4;      // 4-way K split (144 each)
        float2 acc = make_float2(0.f, 0.f);
        for (int k = ks * 144; k < ks * 144 + 144; ++k) {
            float2 v = *(const float2*)&ha[k][t0];
            float w = pW2[k * H_ + col];
            acc.x += w * v.x; acc.y += w * v.y;
        }
        acc.x += __shfl_xor(acc.x, 16, 64); acc.y += __shfl_xor(acc.y, 16, 64);
        acc.x += __shfl_xor(acc.x, 32, 64); acc.y += __shfl_xor(acc.y, 32, 64);
        if (cthr < 16) {
            float b = pb2[col];
            float2 o = make_float2(tanhf(acc.x + b), tanhf(acc.y + b));
            *(float2*)&comb17[1 + col][t0] = o;
        }
        if (cthr == 16) {
            #pragma unroll
            for (int j = 0; j < 2; ++j) {
                int t = t0 + j;
                int id = ids[tok0 + t];
                float c = (float)counts[id];
                if (c < 1.f) c = 1.f;
                comb17[0][t] = log1pf(c);
            }
        }
    }
    __syncthreads();

    // ---- phase 3: LayerNorm(17), one thread per token ----
    if (tid < TPB_) {
        float vals[NH1_];
        float s = 0.f;
        #pragma unroll
        for (int i = 0; i < NH1_; ++i) { vals[i] = comb17[i][tid]; s += vals[i]; }
        float mu = s / NH1_;
        float vq = 0.f;
        #pragma unroll
        for (int i = 0; i < NH1_; ++i) { float d = vals[i] - mu; vq += d * d; }
        float r = rsqrtf(vq / NH1_ + LN_EPS_);
        #pragma unroll
        for (int i = 0; i < NH1_; ++i)
            comb17[i][tid] = (vals[i] - mu) * r * lncw[i] + lncb[i];
    }
    __syncthreads();

    // ---- phase 4: h2 = gelu(comb @ fW1 + fb1) [17 -> 512] ----
    // wave = 4 tokens x 256 cols; 17 k fully unrolled, 4 loads/k
    {
        vfloat4 a0 = 0, a1 = 0, a2 = 0, a3 = 0;
        const int cb = (FFN_ / 2) * ch;        // 0 or 256
        #pragma unroll
        for (int k = 0; k < NH1_; ++k) {
            vfloat4 v = *(const vfloat4*)&comb17[k][tq];
            const float* wrow = &fW1[k * FFN_ + cb + cthr];
            a0 += wrow[0] * v; a1 += wrow[64] * v;
            a2 += wrow[128] * v; a3 += wrow[192] * v;
        }
        int col = cb + cthr;
        *(vfloat4*)&h2a[col      ][tq] = gelu4(a0 + fb1[col]);
        *(vfloat4*)&h2a[col +  64][tq] = gelu4(a1 + fb1[col + 64]);
        *(vfloat4*)&h2a[col + 128][tq] = gelu4(a2 + fb1[col + 128]);
        *(vfloat4*)&h2a[col + 192][tq] = gelu4(a3 + fb1[col + 192]);
    }
    __syncthreads();

    // ---- phase 5: h3 = gelu(h2 @ fW2 + fb2) [512 -> 256] ----
    // wave = 4 tokens x 128 cols; fan-2, unroll 4 -> 8 loads in flight
    {
        vfloat4 a0 = 0, a1 = 0;
        const int cb = (FFNH_ / 2) * ch;       // 0 or 128
        #pragma unroll 4
        for (int k = 0; k < FFN_; ++k) {
            vfloat4 v = *(const vfloat4*)&h2a[k][tq];
            const float* wrow = &fW2[k * FFNH_ + cb + cthr];
            a0 += wrow[0] * v;
            a1 += wrow[64] * v;
        }
        int col = cb + cthr;
        *(vfloat4*)&h3a[col     ][tq] = gelu4(a0 + fb2[col]);
        *(vfloat4*)&h3a[col + 64][tq] = gelu4(a1 + fb2[col + 64]);
    }
    __syncthreads();

    // ---- phase 6: mod = tanh(h3 . fW3 + fb3); 32 threads/token ----
    {
        const int tt = tid >> 5;      // 0..15
        const int l  = tid & 31;
        float acc = 0.f;
        #pragma unroll
        for (int r = 0; r < FFNH_ / 32; ++r) {
            int k = l + 32 * r;
            acc += h3a[k][tt] * fW3[k];
        }
        #pragma unroll
        for (int m = 16; m >= 1; m >>= 1) acc += __shfl_xor(acc, m, 64);
        if (l == 0) {
            float mod = tanhf(acc + fb3[0]);
            wout[tok0 + tt] = 1.0f + EPSILON_ * mod;
        }
    }
}

__global__ __launch_bounds__(256) void scale_kernel(
    const vfloat4* __restrict__ in, const float* __restrict__ w,
    vfloat4* __restrict__ out, long total4)
{
    long i = (long)blockIdx.x * blockDim.x + threadIdx.x;
    const long stride = (long)gridDim.x * blockDim.x;
    for (; i < total4; i += stride) {
        long row = i >> 9;                 // / (S/4=512)  -> flat row in [B*H*S)
        int b = (int)(row >> 15);          // / (H*S = 32768)
        int s = (int)(row & (S_ - 1));
        float ww = w[b * S_ + s];
        vfloat4 x = __builtin_nontemporal_load(&in[i]);  // streamed
        x *= ww;
        __builtin_nontemporal_store(x, &out[i]);         // streamed
    }
}

extern "C" void kernel_launch(void* const* d_in, const int* in_sizes, int n_in,
                              void* d_out, int out_size, void* d_ws, size_t ws_size,
                              hipStream_t stream) {
    const float* scores = (const float*)d_in[0];
    const int*   ids    = (const int*)  d_in[1];
    const float* embW   = (const float*)d_in[2];
    const float* lnvw   = (const float*)d_in[3];
    const float* lnvb   = (const float*)d_in[4];
    const float* pW1    = (const float*)d_in[5];
    const float* pb1    = (const float*)d_in[6];
    const float* pW2    = (const float*)d_in[7];
    const float* pb2    = (const float*)d_in[8];
    const float* lncw   = (const float*)d_in[9];
    const float* lncb   = (const float*)d_in[10];
    const float* fW1    = (const float*)d_in[11];
    const float* fb1    = (const float*)d_in[12];
    const float* fW2    = (const float*)d_in[13];
    const float* fb2    = (const float*)d_in[14];
    const float* fW3    = (const float*)d_in[15];
    const float* fb3    = (const float*)d_in[16];

    int*   counts = (int*)d_ws;
    float* wout   = (float*)((char*)d_ws + CTX_ * sizeof(int));

    count_kernel<<<1, 1024, 0, stream>>>(ids, counts);
    token_mlp_kernel<<<NBLK_, 512, 0, stream>>>(
        ids, counts, embW, lnvw, lnvb, pW1, pb1, pW2, pb2,
        lncw, lncb, fW1, fb1, fW2, fb2, fW3, fb3, wout);

    long total4 = (long)B_ * H_ * S_ * S_ / 4;   // 33,554,432 float4s
    scale_kernel<<<2048, 256, 0, stream>>>(
        (const vfloat4*)scores, wout, (vfloat4*)d_out, total4);
}

// Round 7
// 284.547 us; speedup vs baseline: 1.2309x; 1.1124x over previous
//
#include <hip/hip_runtime.h>
#include <math.h>

#define B_ 2
#define H_ 16
#define S_ 2048
#define CTX_ 1024
#define VD_ 288
#define VD2_ 576
#define FFN_ 512
#define FFNH_ 256
#define NH1_ 17
#define EPSILON_ 0.066f
#define LN_EPS_ 1e-5f
#define TPB_ 16                   // tokens per block
#define NBLK_ (B_ * S_ / TPB_)    // 256 blocks

typedef float vfloat4 __attribute__((ext_vector_type(4)));

__device__ __forceinline__ float gelu_exact(float x) {
    return 0.5f * x * (1.0f + erff(x * 0.70710678118654752440f));
}
__device__ __forceinline__ vfloat4 gelu4(vfloat4 v) {
    vfloat4 o;
    o.x = gelu_exact(v.x); o.y = gelu_exact(v.y);
    o.z = gelu_exact(v.z); o.w = gelu_exact(v.w);
    return o;
}

// one-block fused histogram (proven round 4)
__global__ __launch_bounds__(1024) void count_kernel(
    const int* __restrict__ ids, int* __restrict__ counts)
{
    __shared__ int hist[CTX_];
    const int t = threadIdx.x;          // 1024 threads == CTX_
    hist[t] = 0;
    __syncthreads();
    #pragma unroll
    for (int r = 0; r < (B_ * S_) / 1024; ++r)
        atomicAdd(&hist[ids[t + 1024 * r]], 1);
    __syncthreads();
    counts[t] = hist[t];
}

// Round-6 structure (512 thr, TPB=16, 8 waves = 4 token-quads x 2 col-halves)
// with the hot k-loops (P1/P2/P5) manually unrolled: per GROUP of 4-8 k's,
// all weight loads are issued into registers first, then the LDS broadcasts,
// then the FMA block. This amortizes the per-iteration latency stall 4-8x
// without changing math, layout, LDS, or occupancy.
__global__ __launch_bounds__(512) void token_mlp_kernel(
    const int* __restrict__ ids, const int* __restrict__ counts,
    const float* __restrict__ embW,
    const float* __restrict__ lnvw, const float* __restrict__ lnvb,
    const float* __restrict__ pW1, const float* __restrict__ pb1,
    const float* __restrict__ pW2, const float* __restrict__ pb2,
    const float* __restrict__ lncw, const float* __restrict__ lncb,
    const float* __restrict__ fW1, const float* __restrict__ fb1,
    const float* __restrict__ fW2, const float* __restrict__ fb2,
    const float* __restrict__ fW3, const float* __restrict__ fb3,
    float* __restrict__ wout)
{
    // activations transposed: [dim][token]
    __shared__ __align__(16) float va[VD_][TPB_];      // 18.4 KB
    __shared__ __align__(16) float ha[VD2_][TPB_];     // 36.9 KB
    __shared__ __align__(16) float comb17[NH1_][TPB_]; //  1.1 KB
    __shared__ __align__(16) float h2a[FFN_][TPB_];    // 32.8 KB
    __shared__ __align__(16) float h3a[FFNH_][TPB_];   // 16.4 KB
    // total 105.6 KB -> 1 block/CU, 8 waves = 2 waves/SIMD

    const int tid  = threadIdx.x;
    const int tok0 = blockIdx.x * TPB_;
    const int wid  = tid >> 6;     // wave 0..7
    const int cthr = tid & 63;
    const int t0   = (wid & 3) * 2 + (wid >> 2) * 8; // token pair for phase 2
    const int quad = wid & 3;      // token quad for tiled phases
    const int ch   = wid >> 2;     // column half
    const int tq   = quad * 4;

    // ---- phase 0: embedding gather + LayerNorm(288); 32 threads/token ----
    {
        const int tt = tid >> 5;      // 0..15
        const int l  = tid & 31;
        const int id = ids[tok0 + tt];
        float x[9];
        float s = 0.f, sq = 0.f;
        #pragma unroll
        for (int r = 0; r < 9; ++r) {
            float xv = embW[id * VD_ + l + 32 * r];
            x[r] = xv; s += xv; sq += xv * xv;
        }
        #pragma unroll
        for (int m = 16; m >= 1; m >>= 1) {
            s  += __shfl_xor(s,  m, 64);
            sq += __shfl_xor(sq, m, 64);
        }
        float mu   = s * (1.f / VD_);
        float var  = sq * (1.f / VD_) - mu * mu;
        float rstd = rsqrtf(var + LN_EPS_);
        #pragma unroll
        for (int r = 0; r < 9; ++r) {
            int i = l + 32 * r;
            va[i][tt] = (x[r] - mu) * rstd * lnvw[i] + lnvb[i];
        }
    }
    __syncthreads();

    // ---- phase 1: ha = gelu(va @ pW1 + pb1)  [288 -> 576] ----
    // wave = 4 tokens x 288 cols; k unrolled x4 with grouped loads
    {
        vfloat4 a0 = 0, a1 = 0, a2 = 0, a3 = 0, a4 = 0;
        const int cb = (VD2_ / 2) * ch;        // 0 or 288
        const bool extra = (cthr < 32);        // cols cb+256..cb+287
        for (int k = 0; k < VD_; k += 4) {     // 72 groups
            float w0[4], w1[4], w2[4], w3[4], w4[4];
            #pragma unroll
            for (int u = 0; u < 4; ++u) {
                const float* wr = &pW1[(k + u) * VD2_ + cb + cthr];
                w0[u] = wr[0];   w1[u] = wr[64];
                w2[u] = wr[128]; w3[u] = wr[192];
                if (extra) w4[u] = wr[256];
            }
            vfloat4 v[4];
            #pragma unroll
            for (int u = 0; u < 4; ++u) v[u] = *(const vfloat4*)&va[k + u][tq];
            #pragma unroll
            for (int u = 0; u < 4; ++u) {
                a0 += w0[u] * v[u]; a1 += w1[u] * v[u];
                a2 += w2[u] * v[u]; a3 += w3[u] * v[u];
                if (extra) a4 += w4[u] * v[u];
            }
        }
        int col = cb + cthr;
        *(vfloat4*)&ha[col      ][tq] = gelu4(a0 + pb1[col]);
        *(vfloat4*)&ha[col +  64][tq] = gelu4(a1 + pb1[col + 64]);
        *(vfloat4*)&ha[col + 128][tq] = gelu4(a2 + pb1[col + 128]);
        *(vfloat4*)&ha[col + 192][tq] = gelu4(a3 + pb1[col + 192]);
        if (extra)
            *(vfloat4*)&ha[col + 256][tq] = gelu4(a4 + pb1[col + 256]);
    }
    __syncthreads();

    // ---- phase 2: valence = tanh(ha @ pW2 + pb2) [576 -> 16] + occ ----
    // k unrolled x8 with grouped loads (144 = 18 groups)
    {
        const int col = cthr & 15;
        const int ks  = cthr >> 4;      // 4-way K split (144 each)
        float2 acc = make_float2(0.f, 0.f);
        for (int k = ks * 144; k < ks * 144 + 144; k += 8) {
            float w[8]; float2 v[8];
            #pragma unroll
            for (int u = 0; u < 8; ++u) w[u] = pW2[(k + u) * H_ + col];
            #pragma unroll
            for (int u = 0; u < 8; ++u) v[u] = *(const float2*)&ha[k + u][t0];
            #pragma unroll
            for (int u = 0; u < 8; ++u) {
                acc.x += w[u] * v[u].x; acc.y += w[u] * v[u].y;
            }
        }
        acc.x += __shfl_xor(acc.x, 16, 64); acc.y += __shfl_xor(acc.y, 16, 64);
        acc.x += __shfl_xor(acc.x, 32, 64); acc.y += __shfl_xor(acc.y, 32, 64);
        if (cthr < 16) {
            float b = pb2[col];
            float2 o = make_float2(tanhf(acc.x + b), tanhf(acc.y + b));
            *(float2*)&comb17[1 + col][t0] = o;
        }
        if (cthr == 16) {
            #pragma unroll
            for (int j = 0; j < 2; ++j) {
                int t = t0 + j;
                int id = ids[tok0 + t];
                float c = (float)counts[id];
                if (c < 1.f) c = 1.f;
                comb17[0][t] = log1pf(c);
            }
        }
    }
    __syncthreads();

    // ---- phase 3: LayerNorm(17), one thread per token ----
    if (tid < TPB_) {
        float vals[NH1_];
        float s = 0.f;
        #pragma unroll
        for (int i = 0; i < NH1_; ++i) { vals[i] = comb17[i][tid]; s += vals[i]; }
        float mu = s / NH1_;
        float vq = 0.f;
        #pragma unroll
        for (int i = 0; i < NH1_; ++i) { float d = vals[i] - mu; vq += d * d; }
        float r = rsqrtf(vq / NH1_ + LN_EPS_);
        #pragma unroll
        for (int i = 0; i < NH1_; ++i)
            comb17[i][tid] = (vals[i] - mu) * r * lncw[i] + lncb[i];
    }
    __syncthreads();

    // ---- phase 4: h2 = gelu(comb @ fW1 + fb1) [17 -> 512] ----
    // wave = 4 tokens x 256 cols; 17 k fully unrolled
    {
        vfloat4 a0 = 0, a1 = 0, a2 = 0, a3 = 0;
        const int cb = (FFN_ / 2) * ch;        // 0 or 256
        #pragma unroll
        for (int k = 0; k < NH1_; ++k) {
            vfloat4 v = *(const vfloat4*)&comb17[k][tq];
            const float* wrow = &fW1[k * FFN_ + cb + cthr];
            a0 += wrow[0] * v; a1 += wrow[64] * v;
            a2 += wrow[128] * v; a3 += wrow[192] * v;
        }
        int col = cb + cthr;
        *(vfloat4*)&h2a[col      ][tq] = gelu4(a0 + fb1[col]);
        *(vfloat4*)&h2a[col +  64][tq] = gelu4(a1 + fb1[col + 64]);
        *(vfloat4*)&h2a[col + 128][tq] = gelu4(a2 + fb1[col + 128]);
        *(vfloat4*)&h2a[col + 192][tq] = gelu4(a3 + fb1[col + 192]);
    }
    __syncthreads();

    // ---- phase 5: h3 = gelu(h2 @ fW2 + fb2) [512 -> 256] ----
    // wave = 4 tokens x 128 cols; k unrolled x8 with grouped loads (64 groups)
    {
        vfloat4 a0 = 0, a1 = 0;
        const int cb = (FFNH_ / 2) * ch;       // 0 or 128
        for (int k = 0; k < FFN_; k += 8) {
            float w0[8], w1[8]; vfloat4 v[8];
            #pragma unroll
            for (int u = 0; u < 8; ++u) {
                const float* wr = &fW2[(k + u) * FFNH_ + cb + cthr];
                w0[u] = wr[0]; w1[u] = wr[64];
            }
            #pragma unroll
            for (int u = 0; u < 8; ++u) v[u] = *(const vfloat4*)&h2a[k + u][tq];
            #pragma unroll
            for (int u = 0; u < 8; ++u) {
                a0 += w0[u] * v[u];
                a1 += w1[u] * v[u];
            }
        }
        int col = cb + cthr;
        *(vfloat4*)&h3a[col     ][tq] = gelu4(a0 + fb2[col]);
        *(vfloat4*)&h3a[col + 64][tq] = gelu4(a1 + fb2[col + 64]);
    }
    __syncthreads();

    // ---- phase 6: mod = tanh(h3 . fW3 + fb3); 32 threads/token ----
    {
        const int tt = tid >> 5;      // 0..15
        const int l  = tid & 31;
        float acc = 0.f;
        #pragma unroll
        for (int r = 0; r < FFNH_ / 32; ++r) {
            int k = l + 32 * r;
            acc += h3a[k][tt] * fW3[k];
        }
        #pragma unroll
        for (int m = 16; m >= 1; m >>= 1) acc += __shfl_xor(acc, m, 64);
        if (l == 0) {
            float mod = tanhf(acc + fb3[0]);
            wout[tok0 + tt] = 1.0f + EPSILON_ * mod;
        }
    }
}

__global__ __launch_bounds__(256) void scale_kernel(
    const vfloat4* __restrict__ in, const float* __restrict__ w,
    vfloat4* __restrict__ out, long total4)
{
    long i = (long)blockIdx.x * blockDim.x + threadIdx.x;
    const long stride = (long)gridDim.x * blockDim.x;
    for (; i < total4; i += stride) {
        long row = i >> 9;                 // / (S/4=512)  -> flat row in [B*H*S)
        int b = (int)(row >> 15);          // / (H*S = 32768)
        int s = (int)(row & (S_ - 1));
        float ww = w[b * S_ + s];
        vfloat4 x = __builtin_nontemporal_load(&in[i]);  // streamed
        x *= ww;
        __builtin_nontemporal_store(x, &out[i]);         // streamed
    }
}

extern "C" void kernel_launch(void* const* d_in, const int* in_sizes, int n_in,
                              void* d_out, int out_size, void* d_ws, size_t ws_size,
                              hipStream_t stream) {
    const float* scores = (const float*)d_in[0];
    const int*   ids    = (const int*)  d_in[1];
    const float* embW   = (const float*)d_in[2];
    const float* lnvw   = (const float*)d_in[3];
    const float* lnvb   = (const float*)d_in[4];
    const float* pW1    = (const float*)d_in[5];
    const float* pb1    = (const float*)d_in[6];
    const float* pW2    = (const float*)d_in[7];
    const float* pb2    = (const float*)d_in[8];
    const float* lncw   = (const float*)d_in[9];
    const float* lncb   = (const float*)d_in[10];
    const float* fW1    = (const float*)d_in[11];
    const float* fb1    = (const float*)d_in[12];
    const float* fW2    = (const float*)d_in[13];
    const float* fb2    = (const float*)d_in[14];
    const float* fW3    = (const float*)d_in[15];
    const float* fb3    = (const float*)d_in[16];

    int*   counts = (int*)d_ws;
    float* wout   = (float*)((char*)d_ws + CTX_ * sizeof(int));

    count_kernel<<<1, 1024, 0, stream>>>(ids, counts);
    token_mlp_kernel<<<NBLK_, 512, 0, stream>>>(
        ids, counts, embW, lnvw, lnvb, pW1, pb1, pW2, pb2,
        lncw, lncb, fW1, fb1, fW2, fb2, fW3, fb3, wout);

    long total4 = (long)B_ * H_ * S_ * S_ / 4;   // 33,554,432 float4s
    scale_kernel<<<2048, 256, 0, stream>>>(
        (const vfloat4*)scores, wout, (vfloat4*)d_out, total4);
}